// Round 2
// baseline (58.686 us; speedup 1.0000x reference)
//
#include <hip/hip_runtime.h>
#include <hip/hip_bf16.h>
#include <math.h>

#define HIDDEN 2048
#define NEXP   64
#define NTOK   16384

typedef __attribute__((ext_vector_type(8))) _Float16 f16x8;  // 8 f16 = 4 VGPR (MFMA A/B frag)
typedef __attribute__((ext_vector_type(4))) float   f32x4;   // MFMA C/D frag

// 2-way fp16 RNE split: x = h + l + O(2^-22). Residual exact (Sterbenz), l may be subnormal (ok).
__device__ __forceinline__ void split2_f16(float4 f0, float4 f1, f16x8& h, f16x8& l) {
    float e[8] = {f0.x, f0.y, f0.z, f0.w, f1.x, f1.y, f1.z, f1.w};
    f16x8 hv, lv;
#pragma unroll
    for (int i = 0; i < 8; ++i) {
        _Float16 hh = (_Float16)e[i];        // v_cvt_f16_f32 (RNE)
        float r = e[i] - (float)hh;          // exact residual
        hv[i] = hh;
        lv[i] = (_Float16)r;
    }
    h = hv; l = lv;
}

// ---------------- Kernel 0: w [64][2048] fp32 -> wh/wl f16x8 slots, pre-swizzled ----------------
// Slot (c, e, kgp) holds w[e][c*64 + (kgp^(e&7))*8 .. +7]; flat = c*512 + e*8 + kgp.
// Linear LDS image for global_load_lds; XOR keeps B ds_read_b128 at 2-way (free).
__global__ __launch_bounds__(256) void prep_kernel(
    const float* __restrict__ gw, uint4* __restrict__ wh, uint4* __restrict__ wl)
{
    const int gid = blockIdx.x * 256 + threadIdx.x;   // 0..16383
    const int c   = gid >> 9;
    const int e   = (gid >> 3) & 63;
    const int kgp = gid & 7;
    const int kg  = kgp ^ (e & 7);
    const float* src = gw + (size_t)e * HIDDEN + c * 64 + kg * 8;
    float4 s0 = *(const float4*)src;
    float4 s1 = *(const float4*)(src + 4);
    f16x8 h, l;
    split2_f16(s0, s1, h, l);
    wh[gid] = __builtin_bit_cast(uint4, h);
    wl[gid] = __builtin_bit_cast(uint4, l);
}

// ---------------- Fused kernel: MFMA GEMM (full K) + bias + top-2 + weights + mask ----------------
// Grid 256 blocks x 256 threads; block owns 64 tokens x all 64 experts x K=2048.
// Wave: 16 tokens x 64 experts. Per ks-step: 8 ds_read_b128 feed 12 MFMAs (hh+hl+lh).
// Double-buffer: stage chunk c+1 during compute of chunk c; one barrier per 64-k chunk.
// Epilogue: logits row-complete in LDS -> top-2 scan -> weights/idx/mask, no partials buffer.
#define STAGE(cg, bo)                                                                     \
    _Pragma("unroll")                                                                     \
    for (int rr = 0; rr < 2; ++rr) {                                                      \
        const int s = rr * 256 + tid;                                                     \
        __builtin_amdgcn_global_load_lds(                                                 \
            (const __attribute__((address_space(1))) void*)(wh + (size_t)(cg) * 512 + s), \
            (__attribute__((address_space(3))) void*)&Bs[(bo) + s], 16, 0, 0);            \
        __builtin_amdgcn_global_load_lds(                                                 \
            (const __attribute__((address_space(1))) void*)(wl + (size_t)(cg) * 512 + s), \
            (__attribute__((address_space(3))) void*)&Bs[(bo) + 512 + s], 16, 0, 0);      \
    }

__global__ __launch_bounds__(256) void fused_kernel(
    const float* __restrict__ x,     // [NTOK, HIDDEN]
    const uint4* __restrict__ wh,    // [32][64][8] slots (f16 high plane)
    const uint4* __restrict__ wl,    // f16 low plane
    const float* __restrict__ bias_g,
    float* __restrict__ logits,
    float* __restrict__ weights,
    float* __restrict__ idxf,
    float* __restrict__ mask)
{
    __shared__ uint4 Bs[2 * 1024];   // 2 bufs x (h|l x 512 slots) = 32 KB
    __shared__ float Ls[64][65];     // block's 64x64 logit tile (+1 pad)
    __shared__ int selA[64], selB[64];

    const int tid = threadIdx.x;
    const int l   = tid & 63;
    const int wv  = tid >> 6;
    const int tb0 = blockIdx.x * 64;         // block token base
    const int t0  = tb0 + wv * 16;           // wave token base

    // A: lane l -> row t0+(l&15); k-group (l>>4)*8 within each 32-k step
    const float4* xp = (const float4*)(x + (size_t)(t0 + (l & 15)) * HIDDEN) + ((l >> 4) * 2);

    // B slot base: e=(l&15)+16eg, kgp=((ks<<2)|(l>>4))^(l&7); ks XOR'd at use
    const int lb = ((l & 15) << 3) | ((l >> 4) ^ (l & 7));

    f32x4 acc1[4], acc2[4];          // [eg]
#pragma unroll
    for (int eg = 0; eg < 4; ++eg) {
        acc1[eg] = (f32x4){0.f, 0.f, 0.f, 0.f};
        acc2[eg] = (f32x4){0.f, 0.f, 0.f, 0.f};
    }

    // prologue: stage chunk 0 -> buf 0; load chunk 0's A
    STAGE(0, 0)
    float4 a0 = xp[0], a1 = xp[1], a2 = xp[8], a3 = xp[9];
    __syncthreads();

    const int nch = HIDDEN / 64;     // 32 chunks
    for (int c = 0; c < nch; ++c) {
        const int buf = c & 1;
        float4 n0 = a0, n1 = a1, n2 = a2, n3 = a3;
        if (c + 1 < nch) {
            STAGE(c + 1, (buf ^ 1) * 1024)
            const int fb = (c + 1) * 16;
            n0 = xp[fb + 0]; n1 = xp[fb + 1]; n2 = xp[fb + 8]; n3 = xp[fb + 9];
        }

#pragma unroll
        for (int ks = 0; ks < 2; ++ks) {
            f16x8 ah, al;
            split2_f16(ks ? a2 : a0, ks ? a3 : a1, ah, al);
            const int ib = buf * 1024 + (lb ^ (ks << 2));
#pragma unroll
            for (int eg = 0; eg < 4; ++eg) {
                f16x8 bh = __builtin_bit_cast(f16x8, Bs[ib + eg * 128]);
                f16x8 bl = __builtin_bit_cast(f16x8, Bs[ib + 512 + eg * 128]);
                acc1[eg] = __builtin_amdgcn_mfma_f32_16x16x32_f16(ah, bh, acc1[eg], 0, 0, 0); // hh
                acc2[eg] = __builtin_amdgcn_mfma_f32_16x16x32_f16(ah, bl, acc2[eg], 0, 0, 0); // hl
                acc2[eg] = __builtin_amdgcn_mfma_f32_16x16x32_f16(al, bh, acc2[eg], 0, 0, 0); // lh
            }
        }
        a0 = n0; a1 = n1; a2 = n2; a3 = n3;
        __syncthreads();
    }

    // ---- epilogue: logits tile to LDS (bias added); reg (eg,i) -> row wv*16+(l>>4)*4+i, e eg*16+(l&15)
#pragma unroll
    for (int eg = 0; eg < 4; ++eg) {
        const float b = bias_g[eg * 16 + (l & 15)];
#pragma unroll
        for (int i = 0; i < 4; ++i)
            Ls[wv * 16 + (l >> 4) * 4 + i][eg * 16 + (l & 15)] = acc1[eg][i] + acc2[eg][i] + b;
    }
    __syncthreads();

    // logits to global, coalesced float4: 1024 float4 across 256 threads
#pragma unroll
    for (int i = 0; i < 4; ++i) {
        const int idx = i * 256 + tid;
        const int row = idx >> 4;
        const int c4  = (idx & 15) << 2;
        float4 v;
        v.x = Ls[row][c4 + 0];
        v.y = Ls[row][c4 + 1];
        v.z = Ls[row][c4 + 2];
        v.w = Ls[row][c4 + 3];
        *(float4*)&logits[(size_t)(tb0 + row) * NEXP + c4] = v;
    }

    // top-2 per token (threads 0..63; bank stride 65 -> 2-way, free)
    if (tid < 64) {
        const int t = tid;
        float best = -1e30f, second = -1e30f;
        int bi = 0, si = 0;
#pragma unroll
        for (int e = 0; e < NEXP; ++e) {
            float v = Ls[t][e];
            if (v > best)        { second = best; si = bi; best = v; bi = e; }
            else if (v > second) { second = v; si = e; }
        }
        float r  = __expf(second - best);   // softmax denom cancels in the ratio
        float w0 = 1.f / (1.f + r);
        float w1 = r / (1.f + r);
        const int tgl = tb0 + t;
        weights[2 * tgl + 0] = w0;
        weights[2 * tgl + 1] = w1;
        idxf[2 * tgl + 0] = (float)bi;
        idxf[2 * tgl + 1] = (float)si;
        selA[t] = bi;
        selB[t] = si;
    }
    __syncthreads();

    // mask: 64 experts x 2 k x 64 tokens; thread -> 8 (e,k) pairs x 4 tokens (float4)
    const int t4 = tid & 15;
    const int pg = tid >> 4;
    int sA0 = selA[4*t4+0], sA1 = selA[4*t4+1], sA2 = selA[4*t4+2], sA3 = selA[4*t4+3];
    int sB0 = selB[4*t4+0], sB1 = selB[4*t4+1], sB2 = selB[4*t4+2], sB3 = selB[4*t4+3];
#pragma unroll
    for (int p = 0; p < 8; ++p) {
        const int pair = pg * 8 + p;
        const int e = pair >> 1;
        const int k = pair & 1;
        const int a0 = k ? sB0 : sA0, a1 = k ? sB1 : sA1, a2 = k ? sB2 : sA2, a3 = k ? sB3 : sA3;
        float4 v;
        v.x = (a0 == e) ? 1.f : 0.f;
        v.y = (a1 == e) ? 1.f : 0.f;
        v.z = (a2 == e) ? 1.f : 0.f;
        v.w = (a3 == e) ? 1.f : 0.f;
        *(float4*)&mask[((size_t)e * 2 + k) * NTOK + tb0 + 4 * t4] = v;
    }
}

extern "C" void kernel_launch(void* const* d_in, const int* in_sizes, int n_in,
                              void* d_out, int out_size, void* d_ws, size_t ws_size,
                              hipStream_t stream) {
    const float* x  = (const float*)d_in[0];   // [16384, 2048]
    const float* gw = (const float*)d_in[1];   // [64, 2048]
    const float* gb = (const float*)d_in[2];   // [64]

    float* out     = (float*)d_out;
    float* logits  = out;                                  // 1048576
    float* weights = out + (size_t)NTOK * NEXP;            // 32768
    float* idxf    = weights + (size_t)NTOK * 2;           // 32768
    float* mask    = idxf + (size_t)NTOK * 2;              // 2097152

    // ws layout: wh | wl (256 KB each)
    uint4* wh = (uint4*)d_ws;
    uint4* wl = wh + 16384;

    prep_kernel<<<64, 256, 0, stream>>>(gw, wh, wl);
    fused_kernel<<<NTOK / 64, 256, 0, stream>>>(x, wh, wl, gb, logits, weights, idxf, mask);
}

// Round 3
// 53.567 us; speedup vs baseline: 1.0956x; 1.0956x over previous
//
#include <hip/hip_runtime.h>
#include <hip/hip_bf16.h>
#include <math.h>

#define HIDDEN 2048
#define NEXP   64
#define NTOK   16384

typedef __attribute__((ext_vector_type(8))) _Float16 f16x8;  // 8 f16 = 4 VGPR (MFMA A/B frag)
typedef __attribute__((ext_vector_type(4))) float   f32x4;   // MFMA C/D frag

// 2-way fp16 RNE split: x = h + l + O(2^-22). Residual exact (Sterbenz), l may be subnormal (ok).
__device__ __forceinline__ void split2_f16(float4 f0, float4 f1, f16x8& h, f16x8& l) {
    float e[8] = {f0.x, f0.y, f0.z, f0.w, f1.x, f1.y, f1.z, f1.w};
    f16x8 hv, lv;
#pragma unroll
    for (int i = 0; i < 8; ++i) {
        _Float16 hh = (_Float16)e[i];        // v_cvt_f16_f32 (RNE)
        float r = e[i] - (float)hh;          // exact residual
        hv[i] = hh;
        lv[i] = (_Float16)r;
    }
    h = hv; l = lv;
}

// ---------------- Kernel 0: w [64][2048] fp32 -> wh/wl f16x8 slots, pre-swizzled ----------------
// Slot (c, e, kgp) holds w[e][c*64 + (kgp^(e&7))*8 .. +7]; flat = c*512 + e*8 + kgp.
// Linear LDS image for global_load_lds; XOR keeps B ds_read_b128 at 2-way (free).
__global__ __launch_bounds__(256) void prep_kernel(
    const float* __restrict__ gw, uint4* __restrict__ wh, uint4* __restrict__ wl)
{
    const int gid = blockIdx.x * 256 + threadIdx.x;   // 0..16383
    const int c   = gid >> 9;
    const int e   = (gid >> 3) & 63;
    const int kgp = gid & 7;
    const int kg  = kgp ^ (e & 7);
    const float* src = gw + (size_t)e * HIDDEN + c * 64 + kg * 8;
    float4 s0 = *(const float4*)src;
    float4 s1 = *(const float4*)(src + 4);
    f16x8 h, l;
    split2_f16(s0, s1, h, l);
    wh[gid] = __builtin_bit_cast(uint4, h);
    wl[gid] = __builtin_bit_cast(uint4, l);
}

// ---------------- Fused kernel: MFMA GEMM (full K) + bias + top-2 + weights + mask ----------------
// Grid 512 blocks x 128 threads (2 waves): 32 tokens/block -> 2 blocks/CU, two independent
// barrier domains per CU so one block's vmcnt(0) drain overlaps the other's stream/compute
// (the 1-domain Round-2 regime exposed full per-chunk latency: 58.7 us).
// Wave: 16 tokens x 64 experts. Per ks-step: 8 ds_read_b128 feed 12 MFMAs (hh+hl+lh).
// Double-buffer: stage chunk c+1 during compute of chunk c; one barrier per 64-k chunk.
// Epilogue: logits row-complete in LDS -> top-2 scan -> weights/idx/mask, no partials buffer.
#define STAGE(cg, bo)                                                                     \
    _Pragma("unroll")                                                                     \
    for (int rr = 0; rr < 4; ++rr) {                                                      \
        const int s = rr * 128 + tid;                                                     \
        __builtin_amdgcn_global_load_lds(                                                 \
            (const __attribute__((address_space(1))) void*)(wh + (size_t)(cg) * 512 + s), \
            (__attribute__((address_space(3))) void*)&Bs[(bo) + s], 16, 0, 0);            \
        __builtin_amdgcn_global_load_lds(                                                 \
            (const __attribute__((address_space(1))) void*)(wl + (size_t)(cg) * 512 + s), \
            (__attribute__((address_space(3))) void*)&Bs[(bo) + 512 + s], 16, 0, 0);      \
    }

__global__ __launch_bounds__(128) void fused_kernel(
    const float* __restrict__ x,     // [NTOK, HIDDEN]
    const uint4* __restrict__ wh,    // [32][64][8] slots (f16 high plane)
    const uint4* __restrict__ wl,    // f16 low plane
    const float* __restrict__ bias_g,
    float* __restrict__ logits,
    float* __restrict__ weights,
    float* __restrict__ idxf,
    float* __restrict__ mask)
{
    __shared__ uint4 Bs[2 * 1024];   // 2 bufs x (h|l x 512 slots) = 32 KB
    __shared__ float Ls[32][65];     // block's 32x64 logit tile (+1 pad)
    __shared__ int selA[32], selB[32];

    const int tid = threadIdx.x;
    const int l   = tid & 63;
    const int wv  = tid >> 6;                // 0..1
    const int tb0 = blockIdx.x * 32;         // block token base
    const int t0  = tb0 + wv * 16;           // wave token base

    // A: lane l -> row t0+(l&15); k-group (l>>4)*8 within each 32-k step
    const float4* xp = (const float4*)(x + (size_t)(t0 + (l & 15)) * HIDDEN) + ((l >> 4) * 2);

    // B slot base: e=(l&15)+16eg, kgp=((ks<<2)|(l>>4))^(l&7); ks XOR'd at use
    const int lb = ((l & 15) << 3) | ((l >> 4) ^ (l & 7));

    f32x4 acc1[4], acc2[4];          // [eg]
#pragma unroll
    for (int eg = 0; eg < 4; ++eg) {
        acc1[eg] = (f32x4){0.f, 0.f, 0.f, 0.f};
        acc2[eg] = (f32x4){0.f, 0.f, 0.f, 0.f};
    }

    // prologue: stage chunk 0 -> buf 0; load chunk 0's A
    STAGE(0, 0)
    float4 a0 = xp[0], a1 = xp[1], a2 = xp[8], a3 = xp[9];
    __syncthreads();

    const int nch = HIDDEN / 64;     // 32 chunks
    for (int c = 0; c < nch; ++c) {
        const int buf = c & 1;
        float4 n0 = a0, n1 = a1, n2 = a2, n3 = a3;
        if (c + 1 < nch) {
            STAGE(c + 1, (buf ^ 1) * 1024)
            const int fb = (c + 1) * 16;
            n0 = xp[fb + 0]; n1 = xp[fb + 1]; n2 = xp[fb + 8]; n3 = xp[fb + 9];
        }

#pragma unroll
        for (int ks = 0; ks < 2; ++ks) {
            f16x8 ah, al;
            split2_f16(ks ? a2 : a0, ks ? a3 : a1, ah, al);
            const int ib = buf * 1024 + (lb ^ (ks << 2));
#pragma unroll
            for (int eg = 0; eg < 4; ++eg) {
                f16x8 bh = __builtin_bit_cast(f16x8, Bs[ib + eg * 128]);
                f16x8 bl = __builtin_bit_cast(f16x8, Bs[ib + 512 + eg * 128]);
                acc1[eg] = __builtin_amdgcn_mfma_f32_16x16x32_f16(ah, bh, acc1[eg], 0, 0, 0); // hh
                acc2[eg] = __builtin_amdgcn_mfma_f32_16x16x32_f16(ah, bl, acc2[eg], 0, 0, 0); // hl
                acc2[eg] = __builtin_amdgcn_mfma_f32_16x16x32_f16(al, bh, acc2[eg], 0, 0, 0); // lh
            }
        }
        a0 = n0; a1 = n1; a2 = n2; a3 = n3;
        __syncthreads();
    }

    // ---- epilogue: logits tile to LDS (bias added); reg (eg,i) -> row wv*16+(l>>4)*4+i, e eg*16+(l&15)
#pragma unroll
    for (int eg = 0; eg < 4; ++eg) {
        const float b = bias_g[eg * 16 + (l & 15)];
#pragma unroll
        for (int i = 0; i < 4; ++i)
            Ls[wv * 16 + (l >> 4) * 4 + i][eg * 16 + (l & 15)] = acc1[eg][i] + acc2[eg][i] + b;
    }
    __syncthreads();

    // logits to global, coalesced float4: 512 float4 across 128 threads
#pragma unroll
    for (int i = 0; i < 4; ++i) {
        const int idx = i * 128 + tid;
        const int row = idx >> 4;
        const int c4  = (idx & 15) << 2;
        float4 v;
        v.x = Ls[row][c4 + 0];
        v.y = Ls[row][c4 + 1];
        v.z = Ls[row][c4 + 2];
        v.w = Ls[row][c4 + 3];
        *(float4*)&logits[(size_t)(tb0 + row) * NEXP + c4] = v;
    }

    // top-2 per token (threads 0..31; bank = (t + e) mod 32 -> conflict-free)
    if (tid < 32) {
        const int t = tid;
        float best = -1e30f, second = -1e30f;
        int bi = 0, si = 0;
#pragma unroll
        for (int e = 0; e < NEXP; ++e) {
            float v = Ls[t][e];
            if (v > best)        { second = best; si = bi; best = v; bi = e; }
            else if (v > second) { second = v; si = e; }
        }
        float r  = __expf(second - best);   // softmax denom cancels in the ratio
        float w0 = 1.f / (1.f + r);
        float w1 = r / (1.f + r);
        const int tgl = tb0 + t;
        weights[2 * tgl + 0] = w0;
        weights[2 * tgl + 1] = w1;
        idxf[2 * tgl + 0] = (float)bi;
        idxf[2 * tgl + 1] = (float)si;
        selA[t] = bi;
        selB[t] = si;
    }
    __syncthreads();

    // mask: 64 experts x 2 k x 32 tokens; thread -> 8 (e,k) pairs x 4 tokens (float4)
    const int t8 = tid & 7;          // token group of 4 (8 groups = 32 tokens)
    const int pg = tid >> 3;         // 0..15, 8 pairs each
    const int b0 = 4 * t8;
    int sA0 = selA[b0+0], sA1 = selA[b0+1], sA2 = selA[b0+2], sA3 = selA[b0+3];
    int sB0 = selB[b0+0], sB1 = selB[b0+1], sB2 = selB[b0+2], sB3 = selB[b0+3];
#pragma unroll
    for (int p = 0; p < 8; ++p) {
        const int pair = pg * 8 + p;
        const int e = pair >> 1;
        const int k = pair & 1;
        const int a0 = k ? sB0 : sA0, a1 = k ? sB1 : sA1, a2 = k ? sB2 : sA2, a3 = k ? sB3 : sA3;
        float4 v;
        v.x = (a0 == e) ? 1.f : 0.f;
        v.y = (a1 == e) ? 1.f : 0.f;
        v.z = (a2 == e) ? 1.f : 0.f;
        v.w = (a3 == e) ? 1.f : 0.f;
        *(float4*)&mask[((size_t)e * 2 + k) * NTOK + tb0 + b0] = v;
    }
}

extern "C" void kernel_launch(void* const* d_in, const int* in_sizes, int n_in,
                              void* d_out, int out_size, void* d_ws, size_t ws_size,
                              hipStream_t stream) {
    const float* x  = (const float*)d_in[0];   // [16384, 2048]
    const float* gw = (const float*)d_in[1];   // [64, 2048]
    const float* gb = (const float*)d_in[2];   // [64]

    float* out     = (float*)d_out;
    float* logits  = out;                                  // 1048576
    float* weights = out + (size_t)NTOK * NEXP;            // 32768
    float* idxf    = weights + (size_t)NTOK * 2;           // 32768
    float* mask    = idxf + (size_t)NTOK * 2;              // 2097152

    // ws layout: wh | wl (256 KB each)
    uint4* wh = (uint4*)d_ws;
    uint4* wl = wh + 16384;

    prep_kernel<<<64, 256, 0, stream>>>(gw, wh, wl);
    fused_kernel<<<NTOK / 32, 128, 0, stream>>>(x, wh, wl, gb, logits, weights, idxf, mask);
}